// Round 11
// baseline (1501.460 us; speedup 1.0000x reference)
//
#include <hip/hip_runtime.h>
#include <hip/hip_bf16.h>
#include <stdint.h>

#define B_TOK 65536
#define DM 1024
#define NC 1024
#define NT 16
#define GAPTHR 0.25f

typedef __attribute__((ext_vector_type(4))) float f32x4;
typedef __attribute__((ext_vector_type(4))) unsigned int u32x4;
typedef __attribute__((ext_vector_type(2))) unsigned int u32x2;
typedef __attribute__((ext_vector_type(4))) unsigned short u16x4;
typedef __attribute__((ext_vector_type(8))) short short8;

#define AS1(p) ((__attribute__((address_space(1))) void*)(p))
#define AS3(p) ((__attribute__((address_space(3))) void*)(p))

static __device__ inline unsigned short f2bf(float f) {
  __hip_bfloat16 h = __float2bfloat16(f);
  unsigned short u;
  __builtin_memcpy(&u, &h, 2);
  return u;
}
#define PK8(a, b, old, w) __builtin_amdgcn_cvt_pk_fp8_f32((a), (b), (old), (w))

// ---- prep: ternary masks (bit t = pos, bit 16+t = neg) + ternary bf16 matrix S[16][1024] ----
__global__ void k_prep(const float* __restrict__ sigs, unsigned int* __restrict__ mask,
                       unsigned short* __restrict__ Sb) {
  int d = threadIdx.x;
  unsigned int m = 0;
#pragma unroll
  for (int t = 0; t < NT; ++t) {
    float s = sigs[t * DM + d];
    float q = (s > 0.3f) ? 1.0f : ((s < -0.3f) ? -1.0f : 0.0f);
    if (s > 0.3f) m |= 1u << t;
    else if (s < -0.3f) m |= 1u << (16 + t);
    Sb[t * DM + d] = f2bf(q);   // {-1,0,1} exact in bf16
  }
  mask[d] = m;
}

// ---- fused: provisional scores (blocks 0..1023, dual MFMA chains, bf16 exact-ish path)
//      + x->fp8 for GEMM A + W*16->fp8 convert (blocks 1024..1535) ----
__global__ __launch_bounds__(256) void k_pre(const float* __restrict__ x,
    const unsigned short* __restrict__ Sb, unsigned char* __restrict__ xb,
    int* __restrict__ tidx, float* __restrict__ oidx,
    int* __restrict__ fixlist, int* __restrict__ nfix, int* __restrict__ counts,
    const float* __restrict__ W, unsigned char* __restrict__ Wb)
{
  int bid = blockIdx.x;
  int tid = threadIdx.x;
  if (bid >= 1024) {
    // W f32 -> fp8 e4m3 with x16 pre-scale (keeps |W'| in e4m3 normal range)
    const f32x4* W4 = (const f32x4*)W;
    unsigned int* O = (unsigned int*)Wb;
    int n4 = NT * NC * DM / 4;
    for (int i = (bid - 1024) * 256 + tid; i < n4; i += 512 * 256) {
      f32x4 v = W4[i];
      unsigned int p = PK8(v[0] * 16.f, v[1] * 16.f, 0, 0);
      p = PK8(v[2] * 16.f, v[3] * 16.f, p, 1);
      O[i] = p;
    }
    return;
  }
  __shared__ int hist[16];
  if (tid < 16) hist[tid] = 0;
  __syncthreads();

  int w = tid >> 6, l = tid & 63;
  int lr = l & 15, lg = l >> 4;
  int tok0 = bid * 64 + w * 16;

  const float* xr = x + (size_t)(tok0 + lr) * DM + lg * 8;
  unsigned char* xbr = xb + (size_t)(tok0 + lr) * DM + lg * 8;
  const unsigned short* sr = Sb + (size_t)lr * DM + lg * 8;

  // two independent accumulator chains (even/odd kc) -> 2x MFMA ILP + 2x loads in flight
  f32x4 accA = (f32x4){0.f, 0.f, 0.f, 0.f};
  f32x4 accB = (f32x4){0.f, 0.f, 0.f, 0.f};
  for (int kc = 0; kc < 32; kc += 2) {
    f32x4 v0 = *(const f32x4*)(xr + kc * 32);
    f32x4 v1 = *(const f32x4*)(xr + kc * 32 + 4);
    f32x4 v2 = *(const f32x4*)(xr + kc * 32 + 32);
    f32x4 v3 = *(const f32x4*)(xr + kc * 32 + 36);
    short8 a0, a1;
#pragma unroll
    for (int j = 0; j < 4; ++j) {
      a0[j]     = (short)f2bf(v0[j]);
      a0[4 + j] = (short)f2bf(v1[j]);
      a1[j]     = (short)f2bf(v2[j]);
      a1[4 + j] = (short)f2bf(v3[j]);
    }
    // fp8 pack for GEMM A (HW v_cvt_pk_fp8_f32)
    u32x2 p0, p1;
    p0[0] = PK8(v0[0], v0[1], 0, 0); p0[0] = PK8(v0[2], v0[3], p0[0], 1);
    p0[1] = PK8(v1[0], v1[1], 0, 0); p0[1] = PK8(v1[2], v1[3], p0[1], 1);
    p1[0] = PK8(v2[0], v2[1], 0, 0); p1[0] = PK8(v2[2], v2[3], p1[0], 1);
    p1[1] = PK8(v3[0], v3[1], 0, 0); p1[1] = PK8(v3[2], v3[3], p1[1], 1);
    *(u32x2*)(xbr + kc * 32) = p0;
    *(u32x2*)(xbr + kc * 32 + 32) = p1;
    short8 b0 = *(const short8*)(sr + kc * 32);
    short8 b1 = *(const short8*)(sr + kc * 32 + 32);
    accA = __builtin_amdgcn_mfma_f32_16x16x32_bf16(a0, b0, accA, 0, 0, 0);
    accB = __builtin_amdgcn_mfma_f32_16x16x32_bf16(a1, b1, accB, 0, 0, 0);
  }
  f32x4 acc;
#pragma unroll
  for (int i = 0; i < 4; ++i) acc[i] = accA[i] + accB[i];

  // D: lane(lr,lg) reg i = score[token=lg*4+i][tile=lr]. Top-2 reduce over tile axis.
  float m1[4], m2v[4]; int i1[4];
#pragma unroll
  for (int i = 0; i < 4; ++i) { m1[i] = acc[i]; i1[i] = lr; m2v[i] = -1e30f; }
#pragma unroll
  for (int off = 1; off < 16; off <<= 1) {
#pragma unroll
    for (int i = 0; i < 4; ++i) {
      float bm  = __shfl_xor(m1[i], off);
      int   bi  = __shfl_xor(i1[i], off);
      float bm2 = __shfl_xor(m2v[i], off);
      bool bwin = (bm > m1[i]) || (bm == m1[i] && bi < i1[i]);
      float loser = bwin ? m1[i] : bm;
      m2v[i] = fmaxf(fmaxf(m2v[i], bm2), loser);
      if (bwin) { m1[i] = bm; i1[i] = bi; }
    }
  }
  if (lr == 0) {
#pragma unroll
    for (int i = 0; i < 4; ++i) {
      int tok = tok0 + lg * 4 + i;
      tidx[tok] = i1[i];
      oidx[tok] = (float)i1[i];
      atomicAdd(&hist[i1[i]], 1);
      if (m1[i] - m2v[i] < GAPTHR) {
        int p = atomicAdd(nfix, 1);
        fixlist[p] = tok;
      }
    }
  }
  __syncthreads();
  if (tid < 16 && hist[tid]) atomicAdd(&counts[tid], hist[tid]);
}

// ---- exact f64 rescore for close-call tokens; adjusts counts on flip ----
__global__ __launch_bounds__(256) void k_fix(const float* __restrict__ x,
    const unsigned int* __restrict__ mask, const int* __restrict__ fixlist,
    const int* __restrict__ nfix, int* __restrict__ tidx, float* __restrict__ oidx,
    int* __restrict__ counts)
{
  int n = *nfix;
  int l = threadIdx.x & 63;
  int gw = (blockIdx.x * 256 + threadIdx.x) >> 6;
  int nw = (gridDim.x * 256) >> 6;
  int t = l & 15, seg = l >> 4;

  for (int i = gw; i < n; i += nw) {
    int tok = fixlist[i];
    const float* xr = x + (size_t)tok * DM + seg * 256;
    const unsigned int* mr = mask + seg * 256;
    double acc0 = 0.0, acc1 = 0.0;
    for (int j = 0; j < 256; j += 4) {
      f32x4 xv = *(const f32x4*)(xr + j);
      u32x4 mv = *(const u32x4*)(mr + j);
#pragma unroll
      for (int u = 0; u < 4; ++u) {
        double c = ((mv[u] >> t) & 1u) ? (double)xv[u]
                 : (((mv[u] >> (16 + t)) & 1u) ? -(double)xv[u] : 0.0);
        if (u & 1) acc1 += c; else acc0 += c;
      }
    }
    double s = acc0 + acc1;
    s += __shfl_xor(s, 16);
    s += __shfl_xor(s, 32);
    double bv = s; int bi = t;
#pragma unroll
    for (int off = 1; off < 16; off <<= 1) {
      double ov = __shfl_xor(bv, off);
      int   oi = __shfl_xor(bi, off);
      if (ov > bv || (ov == bv && oi < bi)) { bv = ov; bi = oi; }
    }
    if (l == 0) {
      int old = tidx[tok];
      if (bi != old) {
        tidx[tok] = bi;
        oidx[tok] = (float)bi;
        atomicSub(&counts[old], 1);
        atomicAdd(&counts[bi], 1);
      }
    }
  }
}

// ---- padded exclusive scan of counts (pad to 256) ----
__global__ void k_scan(const int* __restrict__ counts, int* __restrict__ offs) {
  if (threadIdx.x == 0) {
    int s = 0;
    for (int t = 0; t < NT; ++t) {
      offs[t] = s;
      s += (counts[t] + 255) & ~255;
    }
    offs[NT] = s;
  }
}

// ---- scatter tokens into per-tile segments (per-block reservation, low contention) ----
__global__ __launch_bounds__(256) void k_place(const int* __restrict__ tidx, const int* __restrict__ offs,
                                               int* __restrict__ cursor, int* __restrict__ perm) {
  __shared__ int h[16], base[16];
  int tid = threadIdx.x;
  if (tid < 16) h[tid] = 0;
  __syncthreads();
  int tok = blockIdx.x * 256 + tid;
  int t = tidx[tok];
  int myloc = atomicAdd(&h[t], 1);
  __syncthreads();
  if (tid < 16 && h[tid]) base[tid] = atomicAdd(&cursor[tid], h[tid]);
  __syncthreads();
  perm[offs[t] + base[t] + myloc] = tok;
}

// ---- grouped GEMM fp8: 256x256 tile, BK=32, 8 waves, ring-4 LDS = 64KB -> 2 blocks/CU ----
// mfma_f32_16x16x32_fp8_fp8 (i64 frags, same 8-elem/lane mapping as bf16 16x16x32).
// fp8 halves LDS ingest (b64 reads, inherently bank-balanced: wave covers whole 32B rows)
// and staging (2 glds/K-tile). Ledger: stage kt+2 during kt; VM(2) at kt end drains kt+1;
// tail kt30 VM0, kt31 none. W was pre-scaled x16 -> epilogue multiplies by 1/16.
__global__ __launch_bounds__(512, 4) void k_gemm(const unsigned char* __restrict__ xb,
    const unsigned char* __restrict__ Wb, const float* __restrict__ bias,
    const int* __restrict__ perm, const int* __restrict__ offs, float* __restrict__ out)
{
  __shared__ unsigned char lds[4][2][256 * 32];    // [slot][A/B][8KB] = 64KB
  int bid0 = blockIdx.x;
  int bid = (bid0 & 7) * 136 + (bid0 >> 3);        // bijective XCD swizzle (1088 = 8*136)
  int mb = bid >> 2, nb = bid & 3;
  int total = offs[NT];
  int m0 = mb << 8;
  if (m0 >= total) return;
  int t = 0;
#pragma unroll
  for (int tt = 0; tt < NT; ++tt) if (m0 >= offs[tt + 1]) t = tt + 1;
  int c0 = nb << 8;
  int tid = threadIdx.x;

  // staging: thread covers row tid>>1 (0..255), 16B-half tid&1 (linear, no swizzle needed)
  int srow = tid >> 1;
  int sk = (tid & 1) * 16;
  int tkA = perm[m0 + srow]; if (tkA < 0) tkA = 0;
  const unsigned char* pA = xb + (size_t)tkA * DM + sk;
  const unsigned char* pB = Wb + (size_t)t * NC * DM + (size_t)(c0 + srow) * DM + sk;

  f32x4 acc[8][4];
#pragma unroll
  for (int m = 0; m < 8; ++m)
#pragma unroll
    for (int n = 0; n < 4; ++n) acc[m][n] = (f32x4){0.f, 0.f, 0.f, 0.f};

  int wid = tid >> 6, l = tid & 63;
  int wr = wid >> 2, wc = wid & 3;                 // 2M x 4N waves; per-wave out 128x64
  int lr = l & 15, lk = l >> 4;
  int wr128 = wr * 128, wc64 = wc * 64;
  int goff = lk * 8;                               // b64 granule within 32B row

#define GLDS(g, lp) __builtin_amdgcn_global_load_lds(AS1(g), AS3(lp), 16, 0, 0)
#define STAGE_A(SS, KT) GLDS(pA + (KT) * 32, &lds[SS][0][tid * 16])
#define STAGE_B(SS, KT) GLDS(pB + (KT) * 32, &lds[SS][1][tid * 16])
#define RD_A(SLOT, M) (*(const long*)&lds[SLOT][0][(wr128 + (M) * 16 + lr) * 32 + goff])
#define RD_B(SLOT, N) (*(const long*)&lds[SLOT][1][(wc64 + (N) * 16 + lr) * 32 + goff])
#define MF(M_, N_, AV, BV) acc[M_][N_] = __builtin_amdgcn_mfma_f32_16x16x32_fp8_fp8(AV, BV, acc[M_][N_], 0, 0, 0)
#define MFMA4(M_, AV) { MF(M_, 0, AV, b0); MF(M_, 1, AV, b1); MF(M_, 2, AV, b2); MF(M_, 3, AV, b3); }
#define VM2() asm volatile("s_waitcnt vmcnt(2)" ::: "memory")
#define VM0() asm volatile("s_waitcnt vmcnt(0)" ::: "memory")

#define KTILE(KT, SLOT, SS, DOSTAGE, VMW) { \
  long b0 = RD_B(SLOT, 0), b1 = RD_B(SLOT, 1), b2 = RD_B(SLOT, 2), b3 = RD_B(SLOT, 3); \
  long a0 = RD_A(SLOT, 0), a1 = RD_A(SLOT, 1); \
  if (DOSTAGE) STAGE_A(SS, (KT) + 2); \
  __builtin_amdgcn_s_setprio(1); \
  MFMA4(0, a0); MFMA4(1, a1); \
  { long a2 = RD_A(SLOT, 2), a3 = RD_A(SLOT, 3); \
    if (DOSTAGE) STAGE_B(SS, (KT) + 2); \
    MFMA4(2, a2); MFMA4(3, a3); } \
  { long a4 = RD_A(SLOT, 4), a5 = RD_A(SLOT, 5); MFMA4(4, a4); MFMA4(5, a5); } \
  { long a6 = RD_A(SLOT, 6), a7 = RD_A(SLOT, 7); MFMA4(6, a6); MFMA4(7, a7); } \
  __builtin_amdgcn_s_setprio(0); \
  VMW; \
  __builtin_amdgcn_s_barrier(); }

  // prologue: stage kt0 -> slot0, kt1 -> slot1; certify kt0 (4 in flight -> 2)
  STAGE_A(0, 0); STAGE_B(0, 0);
  STAGE_A(1, 1); STAGE_B(1, 1);
  VM2();
  __builtin_amdgcn_s_barrier();

#pragma unroll 1
  for (int kt = 0; kt < 28; kt += 4) {
    KTILE(kt + 0, 0, 2, 1, VM2());
    KTILE(kt + 1, 1, 3, 1, VM2());
    KTILE(kt + 2, 2, 0, 1, VM2());
    KTILE(kt + 3, 3, 1, 1, VM2());
  }
  KTILE(28, 0, 2, 1, VM2());
  KTILE(29, 1, 3, 1, VM2());
  KTILE(30, 2, 0, 0, VM0());
  KTILE(31, 3, 1, 0, ((void)0));

  // epilogue: row(token) = m0 + wr*128 + m*16 + lk*4 + j; col = c0 + wc*64 + n*16 + lr
  float bv[4];
#pragma unroll
  for (int n = 0; n < 4; ++n) bv[n] = bias[t * NC + c0 + wc64 + n * 16 + lr];
#pragma unroll
  for (int m = 0; m < 8; ++m) {
#pragma unroll
    for (int j = 0; j < 4; ++j) {
      int prow = m0 + wr128 + m * 16 + lk * 4 + j;
      int tok = perm[prow];
      if (tok >= 0) {
#pragma unroll
        for (int n = 0; n < 4; ++n)
          out[(size_t)tok * NC + c0 + wc64 + n * 16 + lr] = acc[m][n][j] * 0.0625f + bv[n];
      }
    }
  }
}

extern "C" void kernel_launch(void* const* d_in, const int* in_sizes, int n_in,
                              void* d_out, int out_size, void* d_ws, size_t ws_size,
                              hipStream_t stream) {
  const float* x    = (const float*)d_in[0];
  const float* sigs = (const float*)d_in[1];
  const float* W    = (const float*)d_in[2];
  const float* bias = (const float*)d_in[3];
  float* out = (float*)d_out;
  float* oidx = out + (size_t)B_TOK * NC;

  char* ws = (char*)d_ws;
  unsigned char* xb    = (unsigned char*)ws;                     // 67108864 B (fp8)
  unsigned char* Wb    = (unsigned char*)(ws + 67108864);        // 16777216 B (fp8, x16)
  int* perm            = (int*)(ws + 83886080);                  // 278528 B (69632 rows)
  int* tidx            = (int*)(ws + 84164608);                  // 262144 B
  unsigned int* mask   = (unsigned int*)(ws + 84426752);         // 4096 B
  unsigned short* Sb   = (unsigned short*)(ws + 84430848);       // 32768 B
  int* fixlist         = (int*)(ws + 84463616);                  // 262144 B
  int* ctrl            = (int*)(ws + 84725760);                  // counts16 cursor16 offs17 nfix1
  int* counts = ctrl;
  int* cursor = ctrl + 16;
  int* offs   = ctrl + 32;
  int* nfix   = ctrl + 49;

  hipMemsetAsync(perm, 0xFF, 278528, stream);   // perm = -1 (pad marker)
  hipMemsetAsync(ctrl, 0, 256, stream);

  k_prep<<<1, 1024, 0, stream>>>(sigs, mask, Sb);
  k_pre<<<1536, 256, 0, stream>>>(x, Sb, xb, tidx, oidx, fixlist, nfix, counts, W, Wb);
  k_fix<<<512, 256, 0, stream>>>(x, mask, fixlist, nfix, tidx, oidx, counts);
  k_scan<<<1, 64, 0, stream>>>(counts, offs);
  k_place<<<256, 256, 0, stream>>>(tidx, offs, cursor, perm);
  k_gemm<<<dim3(272 * 4), 512, 0, stream>>>(xb, Wb, bias, perm, offs, out);
}

// Round 12
// 318.502 us; speedup vs baseline: 4.7141x; 4.7141x over previous
//
#include <hip/hip_runtime.h>
#include <hip/hip_bf16.h>
#include <stdint.h>

#define B_TOK 65536
#define DM 1024
#define NC 1024
#define NT 16
#define GAPTHR 0.25f

typedef __attribute__((ext_vector_type(4))) float f32x4;
typedef __attribute__((ext_vector_type(4))) unsigned int u32x4;
typedef __attribute__((ext_vector_type(2))) unsigned int u32x2;
typedef __attribute__((ext_vector_type(4))) unsigned short u16x4;
typedef __attribute__((ext_vector_type(8))) short short8;

#define AS1(p) ((__attribute__((address_space(1))) void*)(p))
#define AS3(p) ((__attribute__((address_space(3))) void*)(p))

static __device__ inline unsigned short f2bf(float f) {
  __hip_bfloat16 h = __float2bfloat16(f);
  unsigned short u;
  __builtin_memcpy(&u, &h, 2);
  return u;
}
#define PK8(a, b, old, w) __builtin_amdgcn_cvt_pk_fp8_f32((a), (b), (old), (w))

// ---- prep: ternary masks (bit t = pos, bit 16+t = neg) + ternary bf16 matrix S[16][1024] ----
__global__ void k_prep(const float* __restrict__ sigs, unsigned int* __restrict__ mask,
                       unsigned short* __restrict__ Sb) {
  int d = threadIdx.x;
  unsigned int m = 0;
#pragma unroll
  for (int t = 0; t < NT; ++t) {
    float s = sigs[t * DM + d];
    float q = (s > 0.3f) ? 1.0f : ((s < -0.3f) ? -1.0f : 0.0f);
    if (s > 0.3f) m |= 1u << t;
    else if (s < -0.3f) m |= 1u << (16 + t);
    Sb[t * DM + d] = f2bf(q);   // {-1,0,1} exact in bf16
  }
  mask[d] = m;
}

// ---- fused: provisional scores (blocks 0..1023, dual MFMA chains, bf16 path)
//      + x->fp8 for GEMM A + W*16->fp8 convert (blocks 1024..1535) ----
__global__ __launch_bounds__(256) void k_pre(const float* __restrict__ x,
    const unsigned short* __restrict__ Sb, unsigned char* __restrict__ xb,
    int* __restrict__ tidx, float* __restrict__ oidx,
    int* __restrict__ fixlist, int* __restrict__ nfix, int* __restrict__ counts,
    const float* __restrict__ W, unsigned char* __restrict__ Wb)
{
  int bid = blockIdx.x;
  int tid = threadIdx.x;
  if (bid >= 1024) {
    // W f32 -> fp8 e4m3 with x16 pre-scale (keeps |W'| in e4m3 normal range)
    const f32x4* W4 = (const f32x4*)W;
    unsigned int* O = (unsigned int*)Wb;
    int n4 = NT * NC * DM / 4;
    for (int i = (bid - 1024) * 256 + tid; i < n4; i += 512 * 256) {
      f32x4 v = W4[i];
      unsigned int p = PK8(v[0] * 16.f, v[1] * 16.f, 0, 0);
      p = PK8(v[2] * 16.f, v[3] * 16.f, p, 1);
      O[i] = p;
    }
    return;
  }
  __shared__ int hist[16];
  if (tid < 16) hist[tid] = 0;
  __syncthreads();

  int w = tid >> 6, l = tid & 63;
  int lr = l & 15, lg = l >> 4;
  int tok0 = bid * 64 + w * 16;

  const float* xr = x + (size_t)(tok0 + lr) * DM + lg * 8;
  unsigned char* xbr = xb + (size_t)(tok0 + lr) * DM + lg * 8;
  const unsigned short* sr = Sb + (size_t)lr * DM + lg * 8;

  // two independent accumulator chains (even/odd kc) -> 2x MFMA ILP + 2x loads in flight
  f32x4 accA = (f32x4){0.f, 0.f, 0.f, 0.f};
  f32x4 accB = (f32x4){0.f, 0.f, 0.f, 0.f};
  for (int kc = 0; kc < 32; kc += 2) {
    f32x4 v0 = *(const f32x4*)(xr + kc * 32);
    f32x4 v1 = *(const f32x4*)(xr + kc * 32 + 4);
    f32x4 v2 = *(const f32x4*)(xr + kc * 32 + 32);
    f32x4 v3 = *(const f32x4*)(xr + kc * 32 + 36);
    short8 a0, a1;
#pragma unroll
    for (int j = 0; j < 4; ++j) {
      a0[j]     = (short)f2bf(v0[j]);
      a0[4 + j] = (short)f2bf(v1[j]);
      a1[j]     = (short)f2bf(v2[j]);
      a1[4 + j] = (short)f2bf(v3[j]);
    }
    // fp8 pack for GEMM A (HW v_cvt_pk_fp8_f32)
    u32x2 p0, p1;
    p0[0] = PK8(v0[0], v0[1], 0, 0); p0[0] = PK8(v0[2], v0[3], p0[0], 1);
    p0[1] = PK8(v1[0], v1[1], 0, 0); p0[1] = PK8(v1[2], v1[3], p0[1], 1);
    p1[0] = PK8(v2[0], v2[1], 0, 0); p1[0] = PK8(v2[2], v2[3], p1[0], 1);
    p1[1] = PK8(v3[0], v3[1], 0, 0); p1[1] = PK8(v3[2], v3[3], p1[1], 1);
    *(u32x2*)(xbr + kc * 32) = p0;
    *(u32x2*)(xbr + kc * 32 + 32) = p1;
    short8 b0 = *(const short8*)(sr + kc * 32);
    short8 b1 = *(const short8*)(sr + kc * 32 + 32);
    accA = __builtin_amdgcn_mfma_f32_16x16x32_bf16(a0, b0, accA, 0, 0, 0);
    accB = __builtin_amdgcn_mfma_f32_16x16x32_bf16(a1, b1, accB, 0, 0, 0);
  }
  f32x4 acc;
#pragma unroll
  for (int i = 0; i < 4; ++i) acc[i] = accA[i] + accB[i];

  // D: lane(lr,lg) reg i = score[token=lg*4+i][tile=lr]. Top-2 reduce over tile axis.
  float m1[4], m2v[4]; int i1[4];
#pragma unroll
  for (int i = 0; i < 4; ++i) { m1[i] = acc[i]; i1[i] = lr; m2v[i] = -1e30f; }
#pragma unroll
  for (int off = 1; off < 16; off <<= 1) {
#pragma unroll
    for (int i = 0; i < 4; ++i) {
      float bm  = __shfl_xor(m1[i], off);
      int   bi  = __shfl_xor(i1[i], off);
      float bm2 = __shfl_xor(m2v[i], off);
      bool bwin = (bm > m1[i]) || (bm == m1[i] && bi < i1[i]);
      float loser = bwin ? m1[i] : bm;
      m2v[i] = fmaxf(fmaxf(m2v[i], bm2), loser);
      if (bwin) { m1[i] = bm; i1[i] = bi; }
    }
  }
  if (lr == 0) {
#pragma unroll
    for (int i = 0; i < 4; ++i) {
      int tok = tok0 + lg * 4 + i;
      tidx[tok] = i1[i];
      oidx[tok] = (float)i1[i];
      atomicAdd(&hist[i1[i]], 1);
      if (m1[i] - m2v[i] < GAPTHR) {
        int p = atomicAdd(nfix, 1);
        fixlist[p] = tok;
      }
    }
  }
  __syncthreads();
  if (tid < 16 && hist[tid]) atomicAdd(&counts[tid], hist[tid]);
}

// ---- exact f64 rescore for close-call tokens; adjusts counts on flip ----
__global__ __launch_bounds__(256) void k_fix(const float* __restrict__ x,
    const unsigned int* __restrict__ mask, const int* __restrict__ fixlist,
    const int* __restrict__ nfix, int* __restrict__ tidx, float* __restrict__ oidx,
    int* __restrict__ counts)
{
  int n = *nfix;
  int l = threadIdx.x & 63;
  int gw = (blockIdx.x * 256 + threadIdx.x) >> 6;
  int nw = (gridDim.x * 256) >> 6;
  int t = l & 15, seg = l >> 4;

  for (int i = gw; i < n; i += nw) {
    int tok = fixlist[i];
    const float* xr = x + (size_t)tok * DM + seg * 256;
    const unsigned int* mr = mask + seg * 256;
    double acc0 = 0.0, acc1 = 0.0;
    for (int j = 0; j < 256; j += 4) {
      f32x4 xv = *(const f32x4*)(xr + j);
      u32x4 mv = *(const u32x4*)(mr + j);
#pragma unroll
      for (int u = 0; u < 4; ++u) {
        double c = ((mv[u] >> t) & 1u) ? (double)xv[u]
                 : (((mv[u] >> (16 + t)) & 1u) ? -(double)xv[u] : 0.0);
        if (u & 1) acc1 += c; else acc0 += c;
      }
    }
    double s = acc0 + acc1;
    s += __shfl_xor(s, 16);
    s += __shfl_xor(s, 32);
    double bv = s; int bi = t;
#pragma unroll
    for (int off = 1; off < 16; off <<= 1) {
      double ov = __shfl_xor(bv, off);
      int   oi = __shfl_xor(bi, off);
      if (ov > bv || (ov == bv && oi < bi)) { bv = ov; bi = oi; }
    }
    if (l == 0) {
      int old = tidx[tok];
      if (bi != old) {
        tidx[tok] = bi;
        oidx[tok] = (float)bi;
        atomicSub(&counts[old], 1);
        atomicAdd(&counts[bi], 1);
      }
    }
  }
}

// ---- padded exclusive scan of counts (pad to 256) ----
__global__ void k_scan(const int* __restrict__ counts, int* __restrict__ offs) {
  if (threadIdx.x == 0) {
    int s = 0;
    for (int t = 0; t < NT; ++t) {
      offs[t] = s;
      s += (counts[t] + 255) & ~255;
    }
    offs[NT] = s;
  }
}

// ---- scatter tokens into per-tile segments (per-block reservation, low contention) ----
__global__ __launch_bounds__(256) void k_place(const int* __restrict__ tidx, const int* __restrict__ offs,
                                               int* __restrict__ cursor, int* __restrict__ perm) {
  __shared__ int h[16], base[16];
  int tid = threadIdx.x;
  if (tid < 16) h[tid] = 0;
  __syncthreads();
  int tok = blockIdx.x * 256 + tid;
  int t = tidx[tok];
  int myloc = atomicAdd(&h[t], 1);
  __syncthreads();
  if (tid < 16 && h[tid]) base[tid] = atomicAdd(&cursor[tid], h[tid]);
  __syncthreads();
  perm[offs[t] + base[t] + myloc] = tok;
}

// ---- grouped GEMM fp8: 256x256, BK=32, 8 waves, ring-4 LDS = 64KB, launch_bounds(512,2)
// (R11 spilled acc with (512,4): VGPR cap 128 < 128-reg accumulator. 256 budget -> no spill.)
// b64-read bank fix: phys granule p of row r holds logical p ^ (((r>>2)&1)<<1); read
// goff = (lk ^ (((lr>>2)&1)<<1))*8; staging source 16B block sk = ((tid&1)^((tid>>3)&1))*16
// with LINEAR LDS dest (both-sides swizzle, s even so 16B blocks stay contiguous).
// Residual 2-way conflict (lr vs lr+8) is free. Ledger: stage kt+2 during kt; VM(2)/K-tile.
__global__ __launch_bounds__(512, 2) void k_gemm(const unsigned char* __restrict__ xb,
    const unsigned char* __restrict__ Wb, const float* __restrict__ bias,
    const int* __restrict__ perm, const int* __restrict__ offs, float* __restrict__ out)
{
  __shared__ unsigned char lds[4][2][256 * 32];    // [slot][A/B][8KB] = 64KB
  int bid0 = blockIdx.x;
  int bid = (bid0 & 7) * 136 + (bid0 >> 3);        // bijective XCD swizzle (1088 = 8*136)
  int mb = bid >> 2, nb = bid & 3;
  int total = offs[NT];
  int m0 = mb << 8;
  if (m0 >= total) return;
  int t = 0;
#pragma unroll
  for (int tt = 0; tt < NT; ++tt) if (m0 >= offs[tt + 1]) t = tt + 1;
  int c0 = nb << 8;
  int tid = threadIdx.x;

  // staging: thread covers row tid>>1 (0..255); source 16B block pre-swizzled
  int srow = tid >> 1;
  int sk = (((tid & 1) ^ ((tid >> 3) & 1)) << 4);
  int tkA = perm[m0 + srow]; if (tkA < 0) tkA = 0;
  const unsigned char* pA = xb + (size_t)tkA * DM + sk;
  const unsigned char* pB = Wb + (size_t)t * NC * DM + (size_t)(c0 + srow) * DM + sk;

  f32x4 acc[8][4];
#pragma unroll
  for (int m = 0; m < 8; ++m)
#pragma unroll
    for (int n = 0; n < 4; ++n) acc[m][n] = (f32x4){0.f, 0.f, 0.f, 0.f};

  int wid = tid >> 6, l = tid & 63;
  int wr = wid >> 2, wc = wid & 3;                 // 2M x 4N waves; per-wave out 128x64
  int lr = l & 15, lk = l >> 4;
  int wr128 = wr * 128, wc64 = wc * 64;
  int goff = (lk ^ (((lr >> 2) & 1) << 1)) * 8;    // swizzled b64 granule offset

#define GLDS(g, lp) __builtin_amdgcn_global_load_lds(AS1(g), AS3(lp), 16, 0, 0)
#define STAGE_A(SS, KT) GLDS(pA + (KT) * 32, &lds[SS][0][tid * 16])
#define STAGE_B(SS, KT) GLDS(pB + (KT) * 32, &lds[SS][1][tid * 16])
#define RD_A(SLOT, M) (*(const long*)&lds[SLOT][0][(wr128 + (M) * 16 + lr) * 32 + goff])
#define RD_B(SLOT, N) (*(const long*)&lds[SLOT][1][(wc64 + (N) * 16 + lr) * 32 + goff])
#define MF(M_, N_, AV, BV) acc[M_][N_] = __builtin_amdgcn_mfma_f32_16x16x32_fp8_fp8(AV, BV, acc[M_][N_], 0, 0, 0)
#define MFMA4(M_, AV) { MF(M_, 0, AV, b0); MF(M_, 1, AV, b1); MF(M_, 2, AV, b2); MF(M_, 3, AV, b3); }
#define VM2() asm volatile("s_waitcnt vmcnt(2)" ::: "memory")
#define VM0() asm volatile("s_waitcnt vmcnt(0)" ::: "memory")

#define KTILE(KT, SLOT, SS, DOSTAGE, VMW) { \
  long b0 = RD_B(SLOT, 0), b1 = RD_B(SLOT, 1), b2 = RD_B(SLOT, 2), b3 = RD_B(SLOT, 3); \
  long a0 = RD_A(SLOT, 0), a1 = RD_A(SLOT, 1); \
  if (DOSTAGE) STAGE_A(SS, (KT) + 2); \
  __builtin_amdgcn_s_setprio(1); \
  MFMA4(0, a0); MFMA4(1, a1); \
  { long a2 = RD_A(SLOT, 2), a3 = RD_A(SLOT, 3); \
    if (DOSTAGE) STAGE_B(SS, (KT) + 2); \
    MFMA4(2, a2); MFMA4(3, a3); } \
  { long a4 = RD_A(SLOT, 4), a5 = RD_A(SLOT, 5); MFMA4(4, a4); MFMA4(5, a5); } \
  { long a6 = RD_A(SLOT, 6), a7 = RD_A(SLOT, 7); MFMA4(6, a6); MFMA4(7, a7); } \
  __builtin_amdgcn_s_setprio(0); \
  VMW; \
  __builtin_amdgcn_s_barrier(); }

  // prologue: stage kt0 -> slot0, kt1 -> slot1; certify kt0 (4 in flight -> 2)
  STAGE_A(0, 0); STAGE_B(0, 0);
  STAGE_A(1, 1); STAGE_B(1, 1);
  VM2();
  __builtin_amdgcn_s_barrier();

#pragma unroll 1
  for (int kt = 0; kt < 28; kt += 4) {
    KTILE(kt + 0, 0, 2, 1, VM2());
    KTILE(kt + 1, 1, 3, 1, VM2());
    KTILE(kt + 2, 2, 0, 1, VM2());
    KTILE(kt + 3, 3, 1, 1, VM2());
  }
  KTILE(28, 0, 2, 1, VM2());
  KTILE(29, 1, 3, 1, VM2());
  KTILE(30, 2, 0, 0, VM0());
  KTILE(31, 3, 1, 0, ((void)0));

  // epilogue: row(token) = m0 + wr*128 + m*16 + lk*4 + j; col = c0 + wc*64 + n*16 + lr
  float bv[4];
#pragma unroll
  for (int n = 0; n < 4; ++n) bv[n] = bias[t * NC + c0 + wc64 + n * 16 + lr];
#pragma unroll
  for (int m = 0; m < 8; ++m) {
#pragma unroll
    for (int j = 0; j < 4; ++j) {
      int prow = m0 + wr128 + m * 16 + lk * 4 + j;
      int tok = perm[prow];
      if (tok >= 0) {
#pragma unroll
        for (int n = 0; n < 4; ++n)
          out[(size_t)tok * NC + c0 + wc64 + n * 16 + lr] = acc[m][n][j] * 0.0625f + bv[n];
      }
    }
  }
}

extern "C" void kernel_launch(void* const* d_in, const int* in_sizes, int n_in,
                              void* d_out, int out_size, void* d_ws, size_t ws_size,
                              hipStream_t stream) {
  const float* x    = (const float*)d_in[0];
  const float* sigs = (const float*)d_in[1];
  const float* W    = (const float*)d_in[2];
  const float* bias = (const float*)d_in[3];
  float* out = (float*)d_out;
  float* oidx = out + (size_t)B_TOK * NC;

  char* ws = (char*)d_ws;
  unsigned char* xb    = (unsigned char*)ws;                     // 67108864 B (fp8)
  unsigned char* Wb    = (unsigned char*)(ws + 67108864);        // 16777216 B (fp8, x16)
  int* perm            = (int*)(ws + 83886080);                  // 278528 B (69632 rows)
  int* tidx            = (int*)(ws + 84164608);                  // 262144 B
  unsigned int* mask   = (unsigned int*)(ws + 84426752);         // 4096 B
  unsigned short* Sb   = (unsigned short*)(ws + 84430848);       // 32768 B
  int* fixlist         = (int*)(ws + 84463616);                  // 262144 B
  int* ctrl            = (int*)(ws + 84725760);                  // counts16 cursor16 offs17 nfix1
  int* counts = ctrl;
  int* cursor = ctrl + 16;
  int* offs   = ctrl + 32;
  int* nfix   = ctrl + 49;

  hipMemsetAsync(perm, 0xFF, 278528, stream);   // perm = -1 (pad marker)
  hipMemsetAsync(ctrl, 0, 256, stream);

  k_prep<<<1, 1024, 0, stream>>>(sigs, mask, Sb);
  k_pre<<<1536, 256, 0, stream>>>(x, Sb, xb, tidx, oidx, fixlist, nfix, counts, W, Wb);
  k_fix<<<512, 256, 0, stream>>>(x, mask, fixlist, nfix, tidx, oidx, counts);
  k_scan<<<1, 64, 0, stream>>>(counts, offs);
  k_place<<<256, 256, 0, stream>>>(tidx, offs, cursor, perm);
  k_gemm<<<dim3(272 * 4), 512, 0, stream>>>(xb, Wb, bias, perm, offs, out);
}

// Round 13
// 316.845 us; speedup vs baseline: 4.7388x; 1.0052x over previous
//
#include <hip/hip_runtime.h>
#include <hip/hip_bf16.h>
#include <stdint.h>

#define B_TOK 65536
#define DM 1024
#define NC 1024
#define NT 16
#define GAPTHR 0.25f

typedef __attribute__((ext_vector_type(4))) float f32x4;
typedef __attribute__((ext_vector_type(4))) unsigned int u32x4;
typedef __attribute__((ext_vector_type(2))) unsigned int u32x2;
typedef __attribute__((ext_vector_type(4))) unsigned short u16x4;
typedef __attribute__((ext_vector_type(8))) short short8;

#define AS1(p) ((__attribute__((address_space(1))) void*)(p))
#define AS3(p) ((__attribute__((address_space(3))) void*)(p))

static __device__ inline unsigned short f2bf(float f) {
  __hip_bfloat16 h = __float2bfloat16(f);
  unsigned short u;
  __builtin_memcpy(&u, &h, 2);
  return u;
}
#define PK8(a, b, old, w) __builtin_amdgcn_cvt_pk_fp8_f32((a), (b), (old), (w))

// ---- prep: ternary masks + ternary bf16 matrix S[16][1024]; also zeroes ctrl ----
__global__ void k_prep(const float* __restrict__ sigs, unsigned int* __restrict__ mask,
                       unsigned short* __restrict__ Sb, int* __restrict__ ctrl) {
  int d = threadIdx.x;
  if (d < 64) ctrl[d] = 0;          // counts/cursor/offs/nfix
  unsigned int m = 0;
#pragma unroll
  for (int t = 0; t < NT; ++t) {
    float s = sigs[t * DM + d];
    float q = (s > 0.3f) ? 1.0f : ((s < -0.3f) ? -1.0f : 0.0f);
    if (s > 0.3f) m |= 1u << t;
    else if (s < -0.3f) m |= 1u << (16 + t);
    Sb[t * DM + d] = f2bf(q);   // {-1,0,1} exact in bf16
  }
  mask[d] = m;
}

// ---- fused: provisional scores (blocks 0..1023, dual MFMA chains, bf16 path)
//      + x->fp8 for GEMM A + W*16->fp8 convert (blocks 1024..1535) ----
__global__ __launch_bounds__(256) void k_pre(const float* __restrict__ x,
    const unsigned short* __restrict__ Sb, unsigned char* __restrict__ xb,
    int* __restrict__ tidx, float* __restrict__ oidx,
    int* __restrict__ fixlist, int* __restrict__ nfix, int* __restrict__ counts,
    const float* __restrict__ W, unsigned char* __restrict__ Wb)
{
  int bid = blockIdx.x;
  int tid = threadIdx.x;
  if (bid >= 1024) {
    // W f32 -> fp8 e4m3 with x16 pre-scale (keeps |W'| in e4m3 normal range)
    const f32x4* W4 = (const f32x4*)W;
    unsigned int* O = (unsigned int*)Wb;
    int n4 = NT * NC * DM / 4;
    for (int i = (bid - 1024) * 256 + tid; i < n4; i += 512 * 256) {
      f32x4 v = W4[i];
      unsigned int p = PK8(v[0] * 16.f, v[1] * 16.f, 0, 0);
      p = PK8(v[2] * 16.f, v[3] * 16.f, p, 1);
      O[i] = p;
    }
    return;
  }
  __shared__ int hist[16];
  if (tid < 16) hist[tid] = 0;
  __syncthreads();

  int w = tid >> 6, l = tid & 63;
  int lr = l & 15, lg = l >> 4;
  int tok0 = bid * 64 + w * 16;

  const float* xr = x + (size_t)(tok0 + lr) * DM + lg * 8;
  unsigned char* xbr = xb + (size_t)(tok0 + lr) * DM + lg * 8;
  const unsigned short* sr = Sb + (size_t)lr * DM + lg * 8;

  f32x4 accA = (f32x4){0.f, 0.f, 0.f, 0.f};
  f32x4 accB = (f32x4){0.f, 0.f, 0.f, 0.f};
  for (int kc = 0; kc < 32; kc += 2) {
    f32x4 v0 = *(const f32x4*)(xr + kc * 32);
    f32x4 v1 = *(const f32x4*)(xr + kc * 32 + 4);
    f32x4 v2 = *(const f32x4*)(xr + kc * 32 + 32);
    f32x4 v3 = *(const f32x4*)(xr + kc * 32 + 36);
    short8 a0, a1;
#pragma unroll
    for (int j = 0; j < 4; ++j) {
      a0[j]     = (short)f2bf(v0[j]);
      a0[4 + j] = (short)f2bf(v1[j]);
      a1[j]     = (short)f2bf(v2[j]);
      a1[4 + j] = (short)f2bf(v3[j]);
    }
    u32x2 p0, p1;
    p0[0] = PK8(v0[0], v0[1], 0, 0); p0[0] = PK8(v0[2], v0[3], p0[0], 1);
    p0[1] = PK8(v1[0], v1[1], 0, 0); p0[1] = PK8(v1[2], v1[3], p0[1], 1);
    p1[0] = PK8(v2[0], v2[1], 0, 0); p1[0] = PK8(v2[2], v2[3], p1[0], 1);
    p1[1] = PK8(v3[0], v3[1], 0, 0); p1[1] = PK8(v3[2], v3[3], p1[1], 1);
    *(u32x2*)(xbr + kc * 32) = p0;
    *(u32x2*)(xbr + kc * 32 + 32) = p1;
    short8 b0 = *(const short8*)(sr + kc * 32);
    short8 b1 = *(const short8*)(sr + kc * 32 + 32);
    accA = __builtin_amdgcn_mfma_f32_16x16x32_bf16(a0, b0, accA, 0, 0, 0);
    accB = __builtin_amdgcn_mfma_f32_16x16x32_bf16(a1, b1, accB, 0, 0, 0);
  }
  f32x4 acc;
#pragma unroll
  for (int i = 0; i < 4; ++i) acc[i] = accA[i] + accB[i];

  float m1[4], m2v[4]; int i1[4];
#pragma unroll
  for (int i = 0; i < 4; ++i) { m1[i] = acc[i]; i1[i] = lr; m2v[i] = -1e30f; }
#pragma unroll
  for (int off = 1; off < 16; off <<= 1) {
#pragma unroll
    for (int i = 0; i < 4; ++i) {
      float bm  = __shfl_xor(m1[i], off);
      int   bi  = __shfl_xor(i1[i], off);
      float bm2 = __shfl_xor(m2v[i], off);
      bool bwin = (bm > m1[i]) || (bm == m1[i] && bi < i1[i]);
      float loser = bwin ? m1[i] : bm;
      m2v[i] = fmaxf(fmaxf(m2v[i], bm2), loser);
      if (bwin) { m1[i] = bm; i1[i] = bi; }
    }
  }
  if (lr == 0) {
#pragma unroll
    for (int i = 0; i < 4; ++i) {
      int tok = tok0 + lg * 4 + i;
      tidx[tok] = i1[i];
      oidx[tok] = (float)i1[i];
      atomicAdd(&hist[i1[i]], 1);
      if (m1[i] - m2v[i] < GAPTHR) {
        int p = atomicAdd(nfix, 1);
        fixlist[p] = tok;
      }
    }
  }
  __syncthreads();
  if (tid < 16 && hist[tid]) atomicAdd(&counts[tid], hist[tid]);
}

// ---- exact f64 rescore for close-call tokens; adjusts counts on flip ----
__global__ __launch_bounds__(256) void k_fix(const float* __restrict__ x,
    const unsigned int* __restrict__ mask, const int* __restrict__ fixlist,
    const int* __restrict__ nfix, int* __restrict__ tidx, float* __restrict__ oidx,
    int* __restrict__ counts)
{
  int n = *nfix;
  int l = threadIdx.x & 63;
  int gw = (blockIdx.x * 256 + threadIdx.x) >> 6;
  int nw = (gridDim.x * 256) >> 6;
  int t = l & 15, seg = l >> 4;

  for (int i = gw; i < n; i += nw) {
    int tok = fixlist[i];
    const float* xr = x + (size_t)tok * DM + seg * 256;
    const unsigned int* mr = mask + seg * 256;
    double acc0 = 0.0, acc1 = 0.0;
    for (int j = 0; j < 256; j += 4) {
      f32x4 xv = *(const f32x4*)(xr + j);
      u32x4 mv = *(const u32x4*)(mr + j);
#pragma unroll
      for (int u = 0; u < 4; ++u) {
        double c = ((mv[u] >> t) & 1u) ? (double)xv[u]
                 : (((mv[u] >> (16 + t)) & 1u) ? -(double)xv[u] : 0.0);
        if (u & 1) acc1 += c; else acc0 += c;
      }
    }
    double s = acc0 + acc1;
    s += __shfl_xor(s, 16);
    s += __shfl_xor(s, 32);
    double bv = s; int bi = t;
#pragma unroll
    for (int off = 1; off < 16; off <<= 1) {
      double ov = __shfl_xor(bv, off);
      int   oi = __shfl_xor(bi, off);
      if (ov > bv || (ov == bv && oi < bi)) { bv = ov; bi = oi; }
    }
    if (l == 0) {
      int old = tidx[tok];
      if (bi != old) {
        tidx[tok] = bi;
        oidx[tok] = (float)bi;
        atomicSub(&counts[old], 1);
        atomicAdd(&counts[bi], 1);
      }
    }
  }
}

// ---- padded exclusive scan (pad to 256) + fill pad rows of perm with -1 ----
__global__ void k_scan(const int* __restrict__ counts, int* __restrict__ offs,
                       int* __restrict__ perm) {
  __shared__ int so[NT + 1], sc[NT];
  if (threadIdx.x == 0) {
    int s = 0;
    for (int t = 0; t < NT; ++t) {
      so[t] = s; offs[t] = s;
      sc[t] = counts[t];
      s += (counts[t] + 255) & ~255;
    }
    so[NT] = s; offs[NT] = s;
  }
  __syncthreads();
  for (int t = 0; t < NT; ++t) {
    int start = so[t] + sc[t], end = so[t + 1];
    for (int i = start + threadIdx.x; i < end; i += blockDim.x) perm[i] = -1;
  }
}

// ---- scatter tokens into per-tile segments (per-block reservation, low contention) ----
__global__ __launch_bounds__(256) void k_place(const int* __restrict__ tidx, const int* __restrict__ offs,
                                               int* __restrict__ cursor, int* __restrict__ perm) {
  __shared__ int h[16], base[16];
  int tid = threadIdx.x;
  if (tid < 16) h[tid] = 0;
  __syncthreads();
  int tok = blockIdx.x * 256 + tid;
  int t = tidx[tok];
  int myloc = atomicAdd(&h[t], 1);
  __syncthreads();
  if (tid < 16 && h[tid]) base[tid] = atomicAdd(&cursor[tid], h[tid]);
  __syncthreads();
  perm[offs[t] + base[t] + myloc] = tok;
}

// ---- grouped GEMM fp8: 256x256, BK=32, 8 waves, ring-4 LDS = 64KB, 3-tile prefetch ----
// Stage kt+3 into slot (kt+3)%4 = (kt-1)%4 (freed at kt-1's closing barrier). Steady-state
// in-flight = {kt+1,kt+2,kt+3} = 6 loads; VM(4) drains kt+1 before kt's closing barrier.
// Tail: kt29 VM2, kt30 VM0, kt31 none. Never drain mid-loop.
__global__ __launch_bounds__(512, 2) void k_gemm(const unsigned char* __restrict__ xb,
    const unsigned char* __restrict__ Wb, const float* __restrict__ bias,
    const int* __restrict__ perm, const int* __restrict__ offs, float* __restrict__ out)
{
  __shared__ unsigned char lds[4][2][256 * 32];    // [slot][A/B][8KB] = 64KB
  int bid0 = blockIdx.x;
  int bid = (bid0 & 7) * 136 + (bid0 >> 3);        // bijective XCD swizzle (1088 = 8*136)
  int mb = bid >> 2, nb = bid & 3;
  int total = offs[NT];
  int m0 = mb << 8;
  if (m0 >= total) return;
  int t = 0;
#pragma unroll
  for (int tt = 0; tt < NT; ++tt) if (m0 >= offs[tt + 1]) t = tt + 1;
  int c0 = nb << 8;
  int tid = threadIdx.x;

  // staging: thread covers row tid>>1 (0..255); source 16B block pre-swizzled (1-bit)
  int srow = tid >> 1;
  int sk = (((tid & 1) ^ ((tid >> 3) & 1)) << 4);
  int tkA = perm[m0 + srow]; if (tkA < 0) tkA = 0;
  const unsigned char* pA = xb + (size_t)tkA * DM + sk;
  const unsigned char* pB = Wb + (size_t)t * NC * DM + (size_t)(c0 + srow) * DM + sk;

  f32x4 acc[8][4];
#pragma unroll
  for (int m = 0; m < 8; ++m)
#pragma unroll
    for (int n = 0; n < 4; ++n) acc[m][n] = (f32x4){0.f, 0.f, 0.f, 0.f};

  int wid = tid >> 6, l = tid & 63;
  int wr = wid >> 2, wc = wid & 3;                 // 2M x 4N waves; per-wave out 128x64
  int lr = l & 15, lk = l >> 4;
  int wr128 = wr * 128, wc64 = wc * 64;
  int goff = (lk ^ (((lr >> 2) & 1) << 1)) * 8;    // swizzled b64 granule offset

#define GLDS(g, lp) __builtin_amdgcn_global_load_lds(AS1(g), AS3(lp), 16, 0, 0)
#define STAGE_A(SS, KT) GLDS(pA + (KT) * 32, &lds[SS][0][tid * 16])
#define STAGE_B(SS, KT) GLDS(pB + (KT) * 32, &lds[SS][1][tid * 16])
#define RD_A(SLOT, M) (*(const long*)&lds[SLOT][0][(wr128 + (M) * 16 + lr) * 32 + goff])
#define RD_B(SLOT, N) (*(const long*)&lds[SLOT][1][(wc64 + (N) * 16 + lr) * 32 + goff])
#define MF(M_, N_, AV, BV) acc[M_][N_] = __builtin_amdgcn_mfma_f32_16x16x32_fp8_fp8(AV, BV, acc[M_][N_], 0, 0, 0)
#define MFMA4(M_, AV) { MF(M_, 0, AV, b0); MF(M_, 1, AV, b1); MF(M_, 2, AV, b2); MF(M_, 3, AV, b3); }
#define VM4() asm volatile("s_waitcnt vmcnt(4)" ::: "memory")
#define VM2() asm volatile("s_waitcnt vmcnt(2)" ::: "memory")
#define VM0() asm volatile("s_waitcnt vmcnt(0)" ::: "memory")

#define KTILE(KT, SLOT, SS, DOSTAGE, VMW) { \
  long b0 = RD_B(SLOT, 0), b1 = RD_B(SLOT, 1), b2 = RD_B(SLOT, 2), b3 = RD_B(SLOT, 3); \
  long a0 = RD_A(SLOT, 0), a1 = RD_A(SLOT, 1); \
  if (DOSTAGE) STAGE_A(SS, (KT) + 3); \
  __builtin_amdgcn_s_setprio(1); \
  MFMA4(0, a0); MFMA4(1, a1); \
  { long a2 = RD_A(SLOT, 2), a3 = RD_A(SLOT, 3); \
    if (DOSTAGE) STAGE_B(SS, (KT) + 3); \
    MFMA4(2, a2); MFMA4(3, a3); } \
  { long a4 = RD_A(SLOT, 4), a5 = RD_A(SLOT, 5); MFMA4(4, a4); MFMA4(5, a5); } \
  { long a6 = RD_A(SLOT, 6), a7 = RD_A(SLOT, 7); MFMA4(6, a6); MFMA4(7, a7); } \
  __builtin_amdgcn_s_setprio(0); \
  VMW; \
  __builtin_amdgcn_s_barrier(); }

  // prologue: stage kt0,1,2 -> slots 0,1,2; VM(4) drains kt0's loads; barrier
  STAGE_A(0, 0); STAGE_B(0, 0);
  STAGE_A(1, 1); STAGE_B(1, 1);
  STAGE_A(2, 2); STAGE_B(2, 2);
  VM4();
  __builtin_amdgcn_s_barrier();

#pragma unroll 1
  for (int kt = 0; kt < 28; kt += 4) {
    KTILE(kt + 0, 0, 3, 1, VM4());
    KTILE(kt + 1, 1, 0, 1, VM4());
    KTILE(kt + 2, 2, 1, 1, VM4());
    KTILE(kt + 3, 3, 2, 1, VM4());
  }
  KTILE(28, 0, 3, 1, VM4());
  KTILE(29, 1, 0, 0, VM2());
  KTILE(30, 2, 1, 0, VM0());
  KTILE(31, 3, 2, 0, ((void)0));

  // epilogue: row(token) = m0 + wr*128 + m*16 + lk*4 + j; col = c0 + wc*64 + n*16 + lr
  float bv[4];
#pragma unroll
  for (int n = 0; n < 4; ++n) bv[n] = bias[t * NC + c0 + wc64 + n * 16 + lr];
#pragma unroll
  for (int m = 0; m < 8; ++m) {
#pragma unroll
    for (int j = 0; j < 4; ++j) {
      int prow = m0 + wr128 + m * 16 + lk * 4 + j;
      int tok = perm[prow];
      if (tok >= 0) {
#pragma unroll
        for (int n = 0; n < 4; ++n)
          out[(size_t)tok * NC + c0 + wc64 + n * 16 + lr] = acc[m][n][j] * 0.0625f + bv[n];
      }
    }
  }
}

extern "C" void kernel_launch(void* const* d_in, const int* in_sizes, int n_in,
                              void* d_out, int out_size, void* d_ws, size_t ws_size,
                              hipStream_t stream) {
  const float* x    = (const float*)d_in[0];
  const float* sigs = (const float*)d_in[1];
  const float* W    = (const float*)d_in[2];
  const float* bias = (const float*)d_in[3];
  float* out = (float*)d_out;
  float* oidx = out + (size_t)B_TOK * NC;

  char* ws = (char*)d_ws;
  unsigned char* xb    = (unsigned char*)ws;                     // 67108864 B (fp8)
  unsigned char* Wb    = (unsigned char*)(ws + 67108864);        // 16777216 B (fp8, x16)
  int* perm            = (int*)(ws + 83886080);                  // 278528 B (69632 rows)
  int* tidx            = (int*)(ws + 84164608);                  // 262144 B
  unsigned int* mask   = (unsigned int*)(ws + 84426752);         // 4096 B
  unsigned short* Sb   = (unsigned short*)(ws + 84430848);       // 32768 B
  int* fixlist         = (int*)(ws + 84463616);                  // 262144 B
  int* ctrl            = (int*)(ws + 84725760);                  // counts16 cursor16 offs17 nfix1
  int* counts = ctrl;
  int* cursor = ctrl + 16;
  int* offs   = ctrl + 32;
  int* nfix   = ctrl + 49;

  k_prep<<<1, 1024, 0, stream>>>(sigs, mask, Sb, ctrl);
  k_pre<<<1536, 256, 0, stream>>>(x, Sb, xb, tidx, oidx, fixlist, nfix, counts, W, Wb);
  k_fix<<<512, 256, 0, stream>>>(x, mask, fixlist, nfix, tidx, oidx, counts);
  k_scan<<<1, 256, 0, stream>>>(counts, offs, perm);
  k_place<<<256, 256, 0, stream>>>(tidx, offs, cursor, perm);
  k_gemm<<<dim3(272 * 4), 512, 0, stream>>>(xb, Wb, bias, perm, offs, out);
}